// Round 15
// baseline (108.764 us; speedup 1.0000x reference)
//
#include <hip/hip_runtime.h>
#include <hip/hip_bf16.h>
#include <cstdint>

#define B_   8
#define C_   128
#define H_   64
#define W_   64
#define NPT  9
#define OC   256
#define K_   (C_*NPT)   // 1152
#define HW   (H_*W_)    // 4096

typedef __attribute__((ext_vector_type(8))) short short8;
typedef __attribute__((ext_vector_type(4))) float f32x4;
typedef __attribute__((ext_vector_type(4))) unsigned int u32x4;

static __device__ __forceinline__ unsigned short f2bf(float f) {
    union { float f; unsigned u; } a; a.f = f;
    unsigned r = a.u + 0x7fffu + ((a.u >> 16) & 1u);   // RNE
    return (unsigned short)(r >> 16);
}
static __device__ __forceinline__ float bf2f(unsigned short u) {
    union { unsigned u; float f; } a; a.u = ((unsigned)u) << 16;
    return a.f;
}

// ---------------- Kernel A: fp32 offset conv — R4 arithmetic, 1024 threads ----------------
// block = (b, row-pair i0), 1024 threads = (j 0..63, cg 0..7, p 0..1).
// Per-output FMA chain and reduction order BIT-IDENTICAL to R4's k_offset2 (the former
// per-thread p-loop is now the thread dim; red buffer reused sequentially for p=0,1).
// Same 131072 B LDS -> 1 block/CU, but 16 waves = 4 waves/SIMD (was 2) to hide latency.
__global__ __launch_bounds__(1024, 4) void k_offset3(const float* __restrict__ x,
                                                     const float* __restrict__ pw,
                                                     const float* __restrict__ pb,
                                                     float* __restrict__ off) {
    __shared__ __align__(16) float wlds[128 * 180];   // [c][tap][20 pad] = 92160 B
    __shared__ float red[8 * 64 * 19];                // [cg][j][19 pad]  = 38912 B
    int b = blockIdx.x >> 5;
    int i0 = (blockIdx.x & 31) * 2;
    int t = threadIdx.x;

    for (int idx = t; idx < 128 * 9 * 18; idx += 1024) {
        int c = idx / 162;
        int r = idx - c * 162;
        int tap = r / 18;
        int o = r - tap * 18;
        wlds[c * 180 + tap * 20 + o] = pw[o * K_ + c * 9 + tap];
    }
    __syncthreads();

    int j = t & 63;
    int cg = (t >> 6) & 7;
    int p = t >> 9;
    const float* xb = x + (size_t)b * C_ * HW;
    float acc[18];
#pragma unroll
    for (int o = 0; o < 18; ++o) acc[o] = 0.f;

    for (int cc = 0; cc < 16; ++cc) {
        int c = cg * 16 + cc;
        const float* xc = xb + (size_t)c * HW;
        float xv[3][3];                               // rows i0+p-1 .. i0+p+1
#pragma unroll
        for (int q = 0; q < 3; ++q) {
            int row = i0 + p - 1 + q;
            if (row >= 0 && row < H_) {
                const float* xr = xc + row * W_;
                xv[q][1] = xr[j];
                xv[q][0] = (j > 0)  ? xr[j - 1] : 0.f;
                xv[q][2] = (j < 63) ? xr[j + 1] : 0.f;
            } else {
                xv[q][0] = xv[q][1] = xv[q][2] = 0.f;
            }
        }
        const float* wc = wlds + c * 180;
#pragma unroll
        for (int tap = 0; tap < 9; ++tap) {
            const int kh = tap / 3, kw = tap % 3;
            float w18[20];
            *(f32x4*)(w18 + 0)  = *(const f32x4*)(wc + tap * 20 + 0);
            *(f32x4*)(w18 + 4)  = *(const f32x4*)(wc + tap * 20 + 4);
            *(f32x4*)(w18 + 8)  = *(const f32x4*)(wc + tap * 20 + 8);
            *(f32x4*)(w18 + 12) = *(const f32x4*)(wc + tap * 20 + 12);
            *(f32x4*)(w18 + 16) = *(const f32x4*)(wc + tap * 20 + 16);
            float xval = xv[kh][kw];
#pragma unroll
            for (int o = 0; o < 18; ++o) acc[o] += w18[o] * xval;
        }
    }

    // reduction: red reused sequentially for p2=0,1 — same adds, same g-order as R4
#pragma unroll
    for (int p2 = 0; p2 < 2; ++p2) {
        __syncthreads();
        if (p == p2) {
#pragma unroll
            for (int o = 0; o < 18; ++o) red[(cg * 64 + j) * 19 + o] = acc[o];
        }
        __syncthreads();
        for (int e = t; e < 64 * 18; e += 1024) {
            int jj = e / 18, o = e - jj * 18;
            float s = 0.f;
#pragma unroll
            for (int g = 0; g < 8; ++g) s += red[(g * 64 + jj) * 19 + o];
            off[(((size_t)b * 18 + o) * H_ + (i0 + p2)) * W_ + jj] = s + pb[o];
        }
    }
}

// ---------------- Kernel W: fold BN scale into bf16 weights, K reordered k = n*128 + c ----------------
__global__ __launch_bounds__(256) void k_prepw(const float* __restrict__ cw,
                                               const float* __restrict__ gam,
                                               const float* __restrict__ bet,
                                               const float* __restrict__ mu,
                                               const float* __restrict__ var,
                                               unsigned short* __restrict__ wbf,
                                               float* __restrict__ bias) {
    int idx = blockIdx.x * 256 + threadIdx.x;   // 0 .. 294911
    int oc = idx / K_;
    int r = idx - oc * K_;
    int n = r >> 7;
    int c = r & 127;
    float sc = gam[oc] * rsqrtf(var[oc] + 1e-5f);
    wbf[idx] = f2bf(cw[oc * K_ + c * NPT + n] * sc);
    if (blockIdx.x == 0 && threadIdx.x < OC) {
        int o = threadIdx.x;
        float s = gam[o] * rsqrtf(var[o] + 1e-5f);
        bias[o] = bet[o] - mu[o] * s;
    }
}

// ---------------- Kernel T: x[b][c][i][j] f32 -> xT[b][i*64+j][c] bf16 (verbatim R7/R11) ----------------
__global__ __launch_bounds__(256) void k_transpose(const float* __restrict__ x,
                                                   unsigned short* __restrict__ xT) {
    __shared__ float sp[128][65];
    int b = blockIdx.x >> 6, i = blockIdx.x & 63;
    int t = threadIdx.x;
    const float* xb = x + (size_t)b * C_ * HW + i * 64;
#pragma unroll
    for (int it = 0; it < 8; ++it) {
        int q = it * 256 + t;              // 2048 f32x4 chunks
        int c = q >> 4, j4 = q & 15;
        f32x4 v = *(const f32x4*)(xb + (size_t)c * HW + j4 * 4);
        *(f32x4*)&sp[c][j4 * 4] = v;
    }
    __syncthreads();
    unsigned short* xo = xT + ((size_t)b * HW + i * 64) * C_;
#pragma unroll
    for (int it = 0; it < 4; ++it) {
        int q = it * 256 + t;              // 1024 granule-chunks
        int j = q >> 4, cg = q & 15;
        u32x4 pk;
#pragma unroll
        for (int p2 = 0; p2 < 4; ++p2) {
            pk[p2] = (uint32_t)f2bf(sp[cg * 8 + p2 * 2][j])
                   | ((uint32_t)f2bf(sp[cg * 8 + p2 * 2 + 1][j]) << 16);
        }
        *(u32x4*)(xo + (size_t)j * C_ + cg * 8) = pk;
    }
}

// ---------------- Kernel F: fused gather + MFMA GEMM + BN/SiLU (verbatim R14, green) ----------------
// block = (b, row i): M=64 px, N=256, K in 36 half-steps of 32.
// LDS: A[2][8][64][16B]=16K @0 ; B[3][256][64B]=48K @16384 ; off[1152]f32 @65536. 70144 B.
__global__ __launch_bounds__(512, 4) void k_fused(const unsigned short* __restrict__ xT,
                                                  const float* __restrict__ off,
                                                  const unsigned short* __restrict__ wbf,
                                                  const float* __restrict__ bias,
                                                  float* __restrict__ out) {
    __shared__ __align__(16) char smem[70144];
    int bid = blockIdx.x;
    int wg = (bid & 7) * 64 + (bid >> 3);             // batch-per-XCD swizzle
    int b = wg >> 6;
    int i = wg & 63;
    int tid = threadIdx.x;
    int wv = tid >> 6, lane = tid & 63, j = lane;
    int lrow = lane & 15, lg = lane >> 4;
    const unsigned short* xTb = xT + (size_t)b * HW * C_;
    const char* Bb = (const char*)wbf;
    float* soff = (float*)(smem + 65536);

    auto stageB = [&](int buf, int hs) {
        char* base = smem + 16384 + buf * 16384;
#pragma unroll
        for (int q = 0; q < 2; ++q) {
            int ch = q * 512 + tid;                   // 1024 chunks of 16B
            int row = ch >> 2, slot = ch & 3;
            int src = row * 2304 + hs * 64 + ((slot ^ (row & 3)) * 16);   // pre-swizzled source
            __builtin_amdgcn_global_load_lds(
                (const __attribute__((address_space(1))) uint32_t*)(Bb + src),
                (__attribute__((address_space(3))) uint32_t*)(base + ch * 16), 16, 0, 0);
        }
    };

    short8 tp0, tp1, tp2, tp3;
    float w00, w11, w01, w10;
    auto gather_issue = [&](int kt) {
        int n = kt >> 1;
        int c8 = (kt & 1) * 8 + wv;
        float ox = soff[n * 64 + j];
        float oy = soff[(n + 9) * 64 + j];
        float pxf = (float)(i + n / 3) + ox;
        float pyf = (float)(j + n % 3) + oy;
        float fx = floorf(pxf), fy = floorf(pyf);
        int r0 = max(0, min(63, (int)fx));
        int r1 = max(0, min(63, (int)fx + 1));
        int c0 = max(0, min(63, (int)fy));
        int c1 = max(0, min(63, (int)fy + 1));
        float pxc = fminf(fmaxf(pxf, 0.f), 63.f);
        float pyc = fminf(fmaxf(pyf, 0.f), 63.f);
        float ax = 1.f + ((float)r0 - pxc);
        float bx = 1.f - ((float)r1 - pxc);
        float ay = 1.f + ((float)c0 - pyc);
        float by = 1.f - ((float)c1 - pyc);
        w00 = ax * ay; w11 = bx * by; w01 = ax * by; w10 = bx * ay;
        const unsigned short* g = xTb + c8 * 8;
        tp0 = *(const short8*)(g + (size_t)(r0 * 64 + c0) * C_);
        tp1 = *(const short8*)(g + (size_t)(r1 * 64 + c1) * C_);
        tp2 = *(const short8*)(g + (size_t)(r0 * 64 + c1) * C_);
        tp3 = *(const short8*)(g + (size_t)(r1 * 64 + c0) * C_);
    };
    auto bilinear_write = [&](int kt) {
        u32x4 pk;
#pragma unroll
        for (int p2 = 0; p2 < 4; ++p2) {
            unsigned short rr[2];
#pragma unroll
            for (int e = 0; e < 2; ++e) {
                int ei = p2 * 2 + e;
                float v = w00 * bf2f((unsigned short)tp0[ei])
                        + w11 * bf2f((unsigned short)tp1[ei])
                        + w01 * bf2f((unsigned short)tp2[ei])
                        + w10 * bf2f((unsigned short)tp3[ei]);
                rr[e] = f2bf(v);
            }
            pk[p2] = (uint32_t)rr[0] | ((uint32_t)rr[1] << 16);
        }
        *(u32x4*)(smem + (kt & 1) * 8192 + wv * 1024 + j * 16) = pk;
    };

    f32x4 zero = {0.f, 0.f, 0.f, 0.f};
    f32x4 acc[4][2];
#pragma unroll
    for (int m = 0; m < 4; ++m)
#pragma unroll
        for (int n = 0; n < 2; ++n) acc[m][n] = zero;

    auto compute_half = [&](int abuf, int bbuf, int h) {
        const char* sa = smem + abuf * 8192;
        const char* sb = smem + 16384 + bbuf * 16384;
        short8 afr[4], bfr[2];
#pragma unroll
        for (int m = 0; m < 4; ++m)
            afr[m] = *(const short8*)(sa + (h * 4 + lg) * 1024 + (m * 16 + lrow) * 16);
#pragma unroll
        for (int n = 0; n < 2; ++n) {
            int row = wv * 32 + n * 16 + lrow;
            bfr[n] = *(const short8*)(sb + row * 64 + ((lg ^ (row & 3)) * 16));   // matching swizzled read
        }
#pragma unroll
        for (int m = 0; m < 4; ++m)
#pragma unroll
            for (int n = 0; n < 2; ++n)
                acc[m][n] = __builtin_amdgcn_mfma_f32_16x16x32_bf16(afr[m], bfr[n], acc[m][n], 0, 0, 0);
    };

    // prologue: off -> LDS; B halves 0,1; then A(0); B half 2
    for (int e = tid; e < 1152; e += 512) {
        int plane = e >> 6, jj = e & 63;
        soff[e] = off[(((size_t)b * 18 + plane) * H_ + i) * W_ + jj];
    }
    stageB(0, 0);
    stageB(1, 1);
    __syncthreads();
    gather_issue(0);
    bilinear_write(0);
    stageB(2, 2);
    __syncthreads();

#pragma unroll 6
    for (int kt = 0; kt < 18; ++kt) {
        const int hs0 = 2 * kt;
        // h0
        if (hs0 + 2 < 36) stageB((hs0 + 2) % 3, hs0 + 2);
        if (kt < 17) gather_issue(kt + 1);
        compute_half(kt & 1, hs0 % 3, 0);
        __syncthreads();
        // h1
        if (hs0 + 3 < 36) stageB((hs0 + 3) % 3, hs0 + 3);
        if (kt < 17) bilinear_write(kt + 1);
        compute_half(kt & 1, (hs0 + 1) % 3, 1);
        __syncthreads();
    }

    // epilogue: bias + SiLU
#pragma unroll
    for (int n = 0; n < 2; ++n) {
        int oc = wv * 32 + n * 16 + lrow;
        float bs = bias[oc];
#pragma unroll
        for (int m = 0; m < 4; ++m) {
#pragma unroll
            for (int r = 0; r < 4; ++r) {
                int px = m * 16 + lg * 4 + r;
                float v = acc[m][n][r] + bs;
                float sv = v / (1.f + __expf(-v));
                out[((size_t)b * OC + oc) * HW + i * 64 + px] = sv;
            }
        }
    }
}

extern "C" void kernel_launch(void* const* d_in, const int* in_sizes, int n_in,
                              void* d_out, int out_size, void* d_ws, size_t ws_size,
                              hipStream_t stream) {
    const float* x   = (const float*)d_in[0];
    const float* pw  = (const float*)d_in[1];
    const float* pb  = (const float*)d_in[2];
    const float* cw  = (const float*)d_in[3];
    const float* gam = (const float*)d_in[4];
    const float* bet = (const float*)d_in[5];
    const float* mu  = (const float*)d_in[6];
    const float* var = (const float*)d_in[7];
    float* out = (float*)d_out;

    char* ws = (char*)d_ws;
    float* off           = (float*)ws;                           // 2,359,296 B
    unsigned short* wbf  = (unsigned short*)(ws + 2359296);      //   589,824 B
    float* bias          = (float*)(ws + 2949120);               //     1,024 B
    unsigned short* xT   = (unsigned short*)(ws + 2950144);      // 8,388,608 B

    hipLaunchKernelGGL(k_offset3,   dim3(256),  dim3(1024), 0, stream, x, pw, pb, off);
    hipLaunchKernelGGL(k_prepw,     dim3(1152), dim3(256),  0, stream, cw, gam, bet, mu, var, wbf, bias);
    hipLaunchKernelGGL(k_transpose, dim3(512),  dim3(256),  0, stream, x, xT);
    hipLaunchKernelGGL(k_fused,     dim3(512),  dim3(512),  0, stream, xT, off, wbf, bias, out);
}

// Round 16
// 100.958 us; speedup vs baseline: 1.0773x; 1.0773x over previous
//
#include <hip/hip_runtime.h>
#include <hip/hip_bf16.h>
#include <cstdint>

#define B_   8
#define C_   128
#define H_   64
#define W_   64
#define NPT  9
#define OC   256
#define K_   (C_*NPT)   // 1152
#define HW   (H_*W_)    // 4096

typedef __attribute__((ext_vector_type(8))) short short8;
typedef __attribute__((ext_vector_type(4))) float f32x4;
typedef __attribute__((ext_vector_type(4))) unsigned int u32x4;

static __device__ __forceinline__ unsigned short f2bf(float f) {
    union { float f; unsigned u; } a; a.f = f;
    unsigned r = a.u + 0x7fffu + ((a.u >> 16) & 1u);   // RNE
    return (unsigned short)(r >> 16);
}
static __device__ __forceinline__ float bf2f(unsigned short u) {
    union { unsigned u; float f; } a; a.u = ((unsigned)u) << 16;
    return a.f;
}

// ---------------- Kernel A: fp32 offset conv (R4 arithmetic; +unroll2 +reg headroom) ----------------
// LDS caps this at 1 block/CU (2 waves/SIMD) regardless of VGPRs, so __launch_bounds__(512,2)
// frees the register allocator; unroll-2 on cc overlaps cc+1's loads with cc's FMA chain.
// Per-output FMA sequence is BIT-IDENTICAL to R4/R14 (unroll only reschedules independents).
__global__ __launch_bounds__(512, 2) void k_offset2(const float* __restrict__ x,
                                                    const float* __restrict__ pw,
                                                    const float* __restrict__ pb,
                                                    float* __restrict__ off) {
    __shared__ __align__(16) float wlds[128 * 180];   // [c][tap][20 pad] = 92160 B
    __shared__ float red[8 * 64 * 19];                // [cg][j][19 pad]  = 38912 B
    int b = blockIdx.x >> 5;
    int i0 = (blockIdx.x & 31) * 2;
    int t = threadIdx.x;

    for (int idx = t; idx < 128 * 9 * 18; idx += 512) {
        int c = idx / 162;
        int r = idx - c * 162;
        int tap = r / 18;
        int o = r - tap * 18;
        wlds[c * 180 + tap * 20 + o] = pw[o * K_ + c * 9 + tap];
    }
    __syncthreads();

    int j = t & 63;
    int cg = t >> 6;
    const float* xb = x + (size_t)b * C_ * HW;
    float acc[2][18];
#pragma unroll
    for (int p = 0; p < 2; ++p)
#pragma unroll
        for (int o = 0; o < 18; ++o) acc[p][o] = 0.f;

#pragma unroll 2
    for (int cc = 0; cc < 16; ++cc) {
        int c = cg * 16 + cc;
        const float* xc = xb + (size_t)c * HW;
        float xv[4][3];
#pragma unroll
        for (int q = 0; q < 4; ++q) {
            int row = i0 - 1 + q;
            if (row >= 0 && row < H_) {
                const float* xr = xc + row * W_;
                xv[q][1] = xr[j];
                xv[q][0] = (j > 0)  ? xr[j - 1] : 0.f;
                xv[q][2] = (j < 63) ? xr[j + 1] : 0.f;
            } else {
                xv[q][0] = xv[q][1] = xv[q][2] = 0.f;
            }
        }
        const float* wc = wlds + c * 180;
#pragma unroll
        for (int tap = 0; tap < 9; ++tap) {
            const int kh = tap / 3, kw = tap % 3;
            float w18[20];
            *(f32x4*)(w18 + 0)  = *(const f32x4*)(wc + tap * 20 + 0);
            *(f32x4*)(w18 + 4)  = *(const f32x4*)(wc + tap * 20 + 4);
            *(f32x4*)(w18 + 8)  = *(const f32x4*)(wc + tap * 20 + 8);
            *(f32x4*)(w18 + 12) = *(const f32x4*)(wc + tap * 20 + 12);
            *(f32x4*)(w18 + 16) = *(const f32x4*)(wc + tap * 20 + 16);
#pragma unroll
            for (int p = 0; p < 2; ++p) {
                float xval = xv[p + kh][kw];
#pragma unroll
                for (int o = 0; o < 18; ++o) acc[p][o] += w18[o] * xval;
            }
        }
    }

#pragma unroll
    for (int p = 0; p < 2; ++p) {
        __syncthreads();
#pragma unroll
        for (int o = 0; o < 18; ++o) red[(cg * 64 + j) * 19 + o] = acc[p][o];
        __syncthreads();
        for (int e = t; e < 64 * 18; e += 512) {
            int jj = e / 18, o = e - jj * 18;
            float s = 0.f;
#pragma unroll
            for (int g = 0; g < 8; ++g) s += red[(g * 64 + jj) * 19 + o];
            off[(((size_t)b * 18 + o) * H_ + (i0 + p)) * W_ + jj] = s + pb[o];
        }
    }
}

// ---------------- Kernel W: fold BN scale into bf16 weights, K reordered k = n*128 + c ----------------
__global__ __launch_bounds__(256) void k_prepw(const float* __restrict__ cw,
                                               const float* __restrict__ gam,
                                               const float* __restrict__ bet,
                                               const float* __restrict__ mu,
                                               const float* __restrict__ var,
                                               unsigned short* __restrict__ wbf,
                                               float* __restrict__ bias) {
    int idx = blockIdx.x * 256 + threadIdx.x;   // 0 .. 294911
    int oc = idx / K_;
    int r = idx - oc * K_;
    int n = r >> 7;
    int c = r & 127;
    float sc = gam[oc] * rsqrtf(var[oc] + 1e-5f);
    wbf[idx] = f2bf(cw[oc * K_ + c * NPT + n] * sc);
    if (blockIdx.x == 0 && threadIdx.x < OC) {
        int o = threadIdx.x;
        float s = gam[o] * rsqrtf(var[o] + 1e-5f);
        bias[o] = bet[o] - mu[o] * s;
    }
}

// ---------------- Kernel T: x[b][c][i][j] f32 -> xT[b][i*64+j][c] bf16 (verbatim R7/R11/R14) ----------------
__global__ __launch_bounds__(256) void k_transpose(const float* __restrict__ x,
                                                   unsigned short* __restrict__ xT) {
    __shared__ float sp[128][65];
    int b = blockIdx.x >> 6, i = blockIdx.x & 63;
    int t = threadIdx.x;
    const float* xb = x + (size_t)b * C_ * HW + i * 64;
#pragma unroll
    for (int it = 0; it < 8; ++it) {
        int q = it * 256 + t;              // 2048 f32x4 chunks
        int c = q >> 4, j4 = q & 15;
        f32x4 v = *(const f32x4*)(xb + (size_t)c * HW + j4 * 4);
        *(f32x4*)&sp[c][j4 * 4] = v;
    }
    __syncthreads();
    unsigned short* xo = xT + ((size_t)b * HW + i * 64) * C_;
#pragma unroll
    for (int it = 0; it < 4; ++it) {
        int q = it * 256 + t;              // 1024 granule-chunks
        int j = q >> 4, cg = q & 15;
        u32x4 pk;
#pragma unroll
        for (int p2 = 0; p2 < 4; ++p2) {
            pk[p2] = (uint32_t)f2bf(sp[cg * 8 + p2 * 2][j])
                   | ((uint32_t)f2bf(sp[cg * 8 + p2 * 2 + 1][j]) << 16);
        }
        *(u32x4*)(xo + (size_t)j * C_ + cg * 8) = pk;
    }
}

// ---------------- Kernel F: fused gather + MFMA GEMM + BN/SiLU (verbatim R14, green) ----------------
// block = (b, row i): M=64 px, N=256, K in 36 half-steps of 32.
// LDS: A[2][8][64][16B]=16K @0 ; B[3][256][64B]=48K @16384 ; off[1152]f32 @65536. 70144 B.
// Schedule FROZEN (3-deep B rotation + 2 barriers/half-step): every 2-deep/counted-vmcnt
// variant failed correctness on HW (R8-R10, R12); B-direct-from-global regressed (R13).
__global__ __launch_bounds__(512, 4) void k_fused(const unsigned short* __restrict__ xT,
                                                  const float* __restrict__ off,
                                                  const unsigned short* __restrict__ wbf,
                                                  const float* __restrict__ bias,
                                                  float* __restrict__ out) {
    __shared__ __align__(16) char smem[70144];
    int bid = blockIdx.x;
    int wg = (bid & 7) * 64 + (bid >> 3);             // batch-per-XCD swizzle
    int b = wg >> 6;
    int i = wg & 63;
    int tid = threadIdx.x;
    int wv = tid >> 6, lane = tid & 63, j = lane;
    int lrow = lane & 15, lg = lane >> 4;
    const unsigned short* xTb = xT + (size_t)b * HW * C_;
    const char* Bb = (const char*)wbf;
    float* soff = (float*)(smem + 65536);

    auto stageB = [&](int buf, int hs) {
        char* base = smem + 16384 + buf * 16384;
#pragma unroll
        for (int q = 0; q < 2; ++q) {
            int ch = q * 512 + tid;                   // 1024 chunks of 16B
            int row = ch >> 2, slot = ch & 3;
            int src = row * 2304 + hs * 64 + ((slot ^ (row & 3)) * 16);   // pre-swizzled source
            __builtin_amdgcn_global_load_lds(
                (const __attribute__((address_space(1))) uint32_t*)(Bb + src),
                (__attribute__((address_space(3))) uint32_t*)(base + ch * 16), 16, 0, 0);
        }
    };

    short8 tp0, tp1, tp2, tp3;
    float w00, w11, w01, w10;
    auto gather_issue = [&](int kt) {
        int n = kt >> 1;
        int c8 = (kt & 1) * 8 + wv;
        float ox = soff[n * 64 + j];
        float oy = soff[(n + 9) * 64 + j];
        float pxf = (float)(i + n / 3) + ox;
        float pyf = (float)(j + n % 3) + oy;
        float fx = floorf(pxf), fy = floorf(pyf);
        int r0 = max(0, min(63, (int)fx));
        int r1 = max(0, min(63, (int)fx + 1));
        int c0 = max(0, min(63, (int)fy));
        int c1 = max(0, min(63, (int)fy + 1));
        float pxc = fminf(fmaxf(pxf, 0.f), 63.f);
        float pyc = fminf(fmaxf(pyf, 0.f), 63.f);
        float ax = 1.f + ((float)r0 - pxc);
        float bx = 1.f - ((float)r1 - pxc);
        float ay = 1.f + ((float)c0 - pyc);
        float by = 1.f - ((float)c1 - pyc);
        w00 = ax * ay; w11 = bx * by; w01 = ax * by; w10 = bx * ay;
        const unsigned short* g = xTb + c8 * 8;
        tp0 = *(const short8*)(g + (size_t)(r0 * 64 + c0) * C_);
        tp1 = *(const short8*)(g + (size_t)(r1 * 64 + c1) * C_);
        tp2 = *(const short8*)(g + (size_t)(r0 * 64 + c1) * C_);
        tp3 = *(const short8*)(g + (size_t)(r1 * 64 + c0) * C_);
    };
    auto bilinear_write = [&](int kt) {
        u32x4 pk;
#pragma unroll
        for (int p2 = 0; p2 < 4; ++p2) {
            unsigned short rr[2];
#pragma unroll
            for (int e = 0; e < 2; ++e) {
                int ei = p2 * 2 + e;
                float v = w00 * bf2f((unsigned short)tp0[ei])
                        + w11 * bf2f((unsigned short)tp1[ei])
                        + w01 * bf2f((unsigned short)tp2[ei])
                        + w10 * bf2f((unsigned short)tp3[ei]);
                rr[e] = f2bf(v);
            }
            pk[p2] = (uint32_t)rr[0] | ((uint32_t)rr[1] << 16);
        }
        *(u32x4*)(smem + (kt & 1) * 8192 + wv * 1024 + j * 16) = pk;
    };

    f32x4 zero = {0.f, 0.f, 0.f, 0.f};
    f32x4 acc[4][2];
#pragma unroll
    for (int m = 0; m < 4; ++m)
#pragma unroll
        for (int n = 0; n < 2; ++n) acc[m][n] = zero;

    auto compute_half = [&](int abuf, int bbuf, int h) {
        const char* sa = smem + abuf * 8192;
        const char* sb = smem + 16384 + bbuf * 16384;
        short8 afr[4], bfr[2];
#pragma unroll
        for (int m = 0; m < 4; ++m)
            afr[m] = *(const short8*)(sa + (h * 4 + lg) * 1024 + (m * 16 + lrow) * 16);
#pragma unroll
        for (int n = 0; n < 2; ++n) {
            int row = wv * 32 + n * 16 + lrow;
            bfr[n] = *(const short8*)(sb + row * 64 + ((lg ^ (row & 3)) * 16));   // matching swizzled read
        }
#pragma unroll
        for (int m = 0; m < 4; ++m)
#pragma unroll
            for (int n = 0; n < 2; ++n)
                acc[m][n] = __builtin_amdgcn_mfma_f32_16x16x32_bf16(afr[m], bfr[n], acc[m][n], 0, 0, 0);
    };

    // prologue: off -> LDS; B halves 0,1; then A(0); B half 2
    for (int e = tid; e < 1152; e += 512) {
        int plane = e >> 6, jj = e & 63;
        soff[e] = off[(((size_t)b * 18 + plane) * H_ + i) * W_ + jj];
    }
    stageB(0, 0);
    stageB(1, 1);
    __syncthreads();
    gather_issue(0);
    bilinear_write(0);
    stageB(2, 2);
    __syncthreads();

#pragma unroll 6
    for (int kt = 0; kt < 18; ++kt) {
        const int hs0 = 2 * kt;
        // h0
        if (hs0 + 2 < 36) stageB((hs0 + 2) % 3, hs0 + 2);
        if (kt < 17) gather_issue(kt + 1);
        compute_half(kt & 1, hs0 % 3, 0);
        __syncthreads();
        // h1
        if (hs0 + 3 < 36) stageB((hs0 + 3) % 3, hs0 + 3);
        if (kt < 17) bilinear_write(kt + 1);
        compute_half(kt & 1, (hs0 + 1) % 3, 1);
        __syncthreads();
    }

    // epilogue: bias + SiLU
#pragma unroll
    for (int n = 0; n < 2; ++n) {
        int oc = wv * 32 + n * 16 + lrow;
        float bs = bias[oc];
#pragma unroll
        for (int m = 0; m < 4; ++m) {
#pragma unroll
            for (int r = 0; r < 4; ++r) {
                int px = m * 16 + lg * 4 + r;
                float v = acc[m][n][r] + bs;
                float sv = v / (1.f + __expf(-v));
                out[((size_t)b * OC + oc) * HW + i * 64 + px] = sv;
            }
        }
    }
}

extern "C" void kernel_launch(void* const* d_in, const int* in_sizes, int n_in,
                              void* d_out, int out_size, void* d_ws, size_t ws_size,
                              hipStream_t stream) {
    const float* x   = (const float*)d_in[0];
    const float* pw  = (const float*)d_in[1];
    const float* pb  = (const float*)d_in[2];
    const float* cw  = (const float*)d_in[3];
    const float* gam = (const float*)d_in[4];
    const float* bet = (const float*)d_in[5];
    const float* mu  = (const float*)d_in[6];
    const float* var = (const float*)d_in[7];
    float* out = (float*)d_out;

    char* ws = (char*)d_ws;
    float* off           = (float*)ws;                           // 2,359,296 B
    unsigned short* wbf  = (unsigned short*)(ws + 2359296);      //   589,824 B
    float* bias          = (float*)(ws + 2949120);               //     1,024 B
    unsigned short* xT   = (unsigned short*)(ws + 2950144);      // 8,388,608 B

    hipLaunchKernelGGL(k_offset2,   dim3(256),  dim3(512), 0, stream, x, pw, pb, off);
    hipLaunchKernelGGL(k_prepw,     dim3(1152), dim3(256), 0, stream, cw, gam, bet, mu, var, wbf, bias);
    hipLaunchKernelGGL(k_transpose, dim3(512),  dim3(256), 0, stream, x, xT);
    hipLaunchKernelGGL(k_fused,     dim3(512),  dim3(512), 0, stream, xT, off, wbf, bias, out);
}